// Round 1
// baseline (3209.405 us; speedup 1.0000x reference)
//
#include <hip/hip_runtime.h>

// ---------------------------------------------------------------------------
// SpatioTemporalTransformerXL forward on gfx950.
// Design:
//  - residual stream h stays fp32 in d_out, updated in place
//  - LN kernels emit bf16 x; all GEMMs are bf16 MFMA (16x16x32), fp32 acc
//  - weights pre-transposed+bf16-cast each call (graph-safe, ~40us)
//  - axial attention: per-(group,head) MFMA flash-free kernels, softmax fp32
//    in registers, P round-trips LDS for C/D -> A-operand layout change
// ---------------------------------------------------------------------------

#define AS1 __attribute__((address_space(1)))
#define AS3 __attribute__((address_space(3)))

using bf16x8 = __attribute__((ext_vector_type(8))) short;   // 8 bf16 = 4 VGPRs
using f32x4  = __attribute__((ext_vector_type(4))) float;

__device__ __forceinline__ f32x4 mfma_bf16(bf16x8 a, bf16x8 b, f32x4 c) {
  return __builtin_amdgcn_mfma_f32_16x16x32_bf16(a, b, c, 0, 0, 0);
}

__device__ __forceinline__ void async16(const void* g, void* l) {
  __builtin_amdgcn_global_load_lds((const AS1 void*)g, (AS3 void*)l, 16, 0, 0);
}

// fp32 -> bf16 RNE
__device__ __forceinline__ short f2bs(float f) {
  union { float f; unsigned u; } x; x.f = f;
  unsigned r = x.u + 0x7fffu + ((x.u >> 16) & 1u);
  return (short)(r >> 16);
}

__device__ __forceinline__ f32x4 fzero() {
  f32x4 v; v[0] = 0.f; v[1] = 0.f; v[2] = 0.f; v[3] = 0.f; return v;
}

__device__ __forceinline__ float quad16_max(float v) {
  v = fmaxf(v, __shfl_xor(v, 1));
  v = fmaxf(v, __shfl_xor(v, 2));
  v = fmaxf(v, __shfl_xor(v, 4));
  v = fmaxf(v, __shfl_xor(v, 8));
  return v;
}
__device__ __forceinline__ float quad16_sum(float v) {
  v += __shfl_xor(v, 1); v += __shfl_xor(v, 2);
  v += __shfl_xor(v, 4); v += __shfl_xor(v, 8);
  return v;
}

// ---------------------------------------------------------------------------
// GEMM: C[M,N] = A[M,K](bf16) * BT[N,K]^T(bf16)  + epilogue
// MODE 0: outB = bf16(acc)                       (QKV projections)
// MODE 1: outF = acc + bias[col] + resid         (output proj / FFN2, fp32)
// MODE 2: outB = bf16(gelu_tanh(acc + bias))     (FFN1)
// 128x128 tile, 4 waves (2x2), each wave 64x64 = 4x4 of 16x16x32 MFMA, BK=32.
// ---------------------------------------------------------------------------
template<int MODE>
__global__ __launch_bounds__(256) void gemm_bt(
    const short* __restrict__ A, const short* __restrict__ BT,
    const float* __restrict__ bias, const float* __restrict__ resid,
    float* __restrict__ outF, short* __restrict__ outB,
    int M, int N, int K)
{
  __shared__ __align__(16) short lA[128 * 32];
  __shared__ __align__(16) short lB[128 * 32];
  const int tid  = threadIdx.x;
  const int wave = tid >> 6, lane = tid & 63;
  const int quad = lane >> 4, l16 = lane & 15;
  const int wm = wave >> 1, wn = wave & 1;
  const long bm0 = (long)blockIdx.y * 128;
  const long bn0 = (long)blockIdx.x * 128;
  const int crow = lane >> 2;          // row within 16-row chunk
  const int ck8  = (lane & 3) * 8;     // element col within BK=32

  f32x4 acc[4][4];
#pragma unroll
  for (int i = 0; i < 4; ++i)
#pragma unroll
    for (int j = 0; j < 4; ++j) acc[i][j] = fzero();

  for (int k0 = 0; k0 < K; k0 += 32) {
    __syncthreads();
#pragma unroll
    for (int cc = 0; cc < 2; ++cc) {
      int c = wave * 2 + cc;
      async16(A  + (bm0 + c * 16 + crow) * (long)K + k0 + ck8, (char*)lA + c * 1024);
      async16(BT + (bn0 + c * 16 + crow) * (long)K + k0 + ck8, (char*)lB + c * 1024);
    }
    __syncthreads();
    bf16x8 a[4], b[4];
#pragma unroll
    for (int i = 0; i < 4; ++i)
      a[i] = *(const bf16x8*)&lA[(wm * 64 + i * 16 + l16) * 32 + quad * 8];
#pragma unroll
    for (int j = 0; j < 4; ++j)
      b[j] = *(const bf16x8*)&lB[(wn * 64 + j * 16 + l16) * 32 + quad * 8];
#pragma unroll
    for (int i = 0; i < 4; ++i)
#pragma unroll
      for (int j = 0; j < 4; ++j)
        acc[i][j] = mfma_bf16(a[i], b[j], acc[i][j]);
  }

#pragma unroll
  for (int i = 0; i < 4; ++i)
#pragma unroll
    for (int j = 0; j < 4; ++j)
#pragma unroll
      for (int r = 0; r < 4; ++r) {
        long gr = bm0 + wm * 64 + i * 16 + quad * 4 + r;
        long gc = bn0 + wn * 64 + j * 16 + l16;
        size_t idx = (size_t)gr * N + gc;
        float v = acc[i][j][r];
        if (MODE == 0) {
          outB[idx] = f2bs(v);
        } else if (MODE == 1) {
          outF[idx] = v + bias[gc] + resid[idx];
        } else {
          float t = v + bias[gc];
          float g = 0.5f * t * (1.f + tanhf(0.7978845608f * (t + 0.044715f * t * t * t)));
          outB[idx] = f2bs(g);
        }
      }
}

// ---------------------------------------------------------------------------
// LayerNorm: h fp32 [16384,768] -> bf16 x, one block per row, 256 threads.
// ---------------------------------------------------------------------------
__global__ __launch_bounds__(256) void ln_kernel(
    const float* __restrict__ h, const float* __restrict__ sc,
    const float* __restrict__ bi, short* __restrict__ out)
{
  const int row = blockIdx.x, tid = threadIdx.x;
  const float* hr = h + (long)row * 768;
  float x0 = hr[tid], x1 = hr[tid + 256], x2 = hr[tid + 512];
  __shared__ float red[4];
  float s = x0 + x1 + x2;
#pragma unroll
  for (int m = 32; m >= 1; m >>= 1) s += __shfl_xor(s, m);
  if ((tid & 63) == 0) red[tid >> 6] = s;
  __syncthreads();
  float mean = (red[0] + red[1] + red[2] + red[3]) * (1.f / 768.f);
  float d0 = x0 - mean, d1 = x1 - mean, d2 = x2 - mean;
  float q = d0 * d0 + d1 * d1 + d2 * d2;
#pragma unroll
  for (int m = 32; m >= 1; m >>= 1) q += __shfl_xor(q, m);
  __syncthreads();
  if ((tid & 63) == 0) red[tid >> 6] = q;
  __syncthreads();
  float var = (red[0] + red[1] + red[2] + red[3]) * (1.f / 768.f);
  float inv = rsqrtf(var + 1e-5f);
  long o = (long)row * 768;
  out[o + tid]       = f2bs(d0 * inv * sc[tid]       + bi[tid]);
  out[o + tid + 256] = f2bs(d1 * inv * sc[tid + 256] + bi[tid + 256]);
  out[o + tid + 512] = f2bs(d2 * inv * sc[tid + 512] + bi[tid + 512]);
}

// ---------------------------------------------------------------------------
// Weight transpose + bf16 cast: in fp32 [Kd][Nd] -> out bf16 [Nd][Kd]
// ---------------------------------------------------------------------------
__global__ __launch_bounds__(256) void transpose_w(
    const float* __restrict__ in, short* __restrict__ out, int Kd, int Nd)
{
  __shared__ float t[32][33];
  const int n0 = blockIdx.x * 32, k0 = blockIdx.y * 32;
  const int r = threadIdx.x >> 5, c = threadIdx.x & 31;
#pragma unroll
  for (int rr = 0; rr < 4; ++rr)
    t[r + rr * 8][c] = in[(long)(k0 + r + rr * 8) * Nd + n0 + c];
  __syncthreads();
#pragma unroll
  for (int rr = 0; rr < 4; ++rr)
    out[(long)(n0 + r + rr * 8) * Kd + k0 + c] = f2bs(t[c][r + rr * 8]);
}

// ---------------------------------------------------------------------------
// Space attention: softmax over L=256. Grid (qtile=4, head=12, b*t=64),
// 256 threads = 4 waves; each wave owns 16 q-rows. qkv row stride 2304:
// cols [0,768) Q, [768,1536) K, [1536,2304) V, packed h*64+d.
// ---------------------------------------------------------------------------
__global__ __launch_bounds__(256) void attn_space(
    const short* __restrict__ qkv, short* __restrict__ ao)
{
  __shared__ __align__(16) short VT[64 * 256];      // VT[d][l]
  __shared__ __align__(16) short P[4][16 * 256];    // per-wave P[q][l]
  const int qt = blockIdx.x, hh = blockIdx.y, bt = blockIdx.z;
  const long tok0 = (long)bt * 256;
  const int tid = threadIdx.x, wave = tid >> 6, lane = tid & 63;
  const int quad = lane >> 4, l16 = lane & 15;

  // stage V^T
#pragma unroll
  for (int it = 0; it < 8; ++it) {
    int chunk = it * 256 + tid;
    int vl = chunk >> 3, d8 = (chunk & 7) * 8;
    bf16x8 v = *(const bf16x8*)(qkv + (tok0 + vl) * 2304 + 1536 + hh * 64 + d8);
#pragma unroll
    for (int e = 0; e < 8; ++e) VT[(d8 + e) * 256 + vl] = v[e];
  }

  const int qr = qt * 64 + wave * 16;
  bf16x8 qf[2];
#pragma unroll
  for (int kk = 0; kk < 2; ++kk)
    qf[kk] = *(const bf16x8*)(qkv + (tok0 + qr + l16) * 2304 + hh * 64 + kk * 32 + quad * 8);

  f32x4 S[16];
#pragma unroll
  for (int j = 0; j < 16; ++j) S[j] = fzero();
#pragma unroll
  for (int j = 0; j < 16; ++j)
#pragma unroll
    for (int kk = 0; kk < 2; ++kk) {
      bf16x8 kf = *(const bf16x8*)(qkv + (tok0 + j * 16 + l16) * 2304 + 768 + hh * 64 + kk * 32 + quad * 8);
      S[j] = mfma_bf16(qf[kk], kf, S[j]);
    }

  // softmax rows quad*4+r  (C/D layout: col=l16, row=quad*4+reg)
#pragma unroll
  for (int r = 0; r < 4; ++r) {
    float m = -1e30f;
#pragma unroll
    for (int j = 0; j < 16; ++j) m = fmaxf(m, S[j][r]);
    m = quad16_max(m);
    float sum = 0.f;
#pragma unroll
    for (int j = 0; j < 16; ++j) {
      float e = __expf((S[j][r] - m) * 0.125f);
      S[j][r] = e; sum += e;
    }
    sum = quad16_sum(sum);
    float inv = 1.f / sum;
#pragma unroll
    for (int j = 0; j < 16; ++j)
      P[wave][(quad * 4 + r) * 256 + j * 16 + l16] = f2bs(S[j][r] * inv);
  }
  __syncthreads();

  // O = P (A-layout from LDS) * V (B-layout from VT)
  f32x4 O[4];
#pragma unroll
  for (int jn = 0; jn < 4; ++jn) O[jn] = fzero();
  for (int kk = 0; kk < 8; ++kk) {
    bf16x8 pf = *(const bf16x8*)&P[wave][l16 * 256 + kk * 32 + quad * 8];
#pragma unroll
    for (int jn = 0; jn < 4; ++jn) {
      bf16x8 vf = *(const bf16x8*)&VT[(jn * 16 + l16) * 256 + kk * 32 + quad * 8];
      O[jn] = mfma_bf16(pf, vf, O[jn]);
    }
  }
#pragma unroll
  for (int jn = 0; jn < 4; ++jn)
#pragma unroll
    for (int r = 0; r < 4; ++r) {
      int row = qr + quad * 4 + r;
      ao[(tok0 + row) * 768 + hh * 64 + jn * 16 + l16] = f2bs(O[jn][r]);
    }
}

// ---------------------------------------------------------------------------
// Time attention: softmax over T=32. Grid (l=256, head=12, b=2), 1 wave.
// token(t) = (b*32+t)*256 + l
// ---------------------------------------------------------------------------
__global__ __launch_bounds__(64) void attn_time(
    const short* __restrict__ qkv, short* __restrict__ ao)
{
  __shared__ __align__(16) short VT[64 * 32];   // VT[d][t]
  __shared__ __align__(16) short P[32 * 32];    // P[t_q][t_k]
  const int ll = blockIdx.x, hh = blockIdx.y, b = blockIdx.z;
  const int lane = threadIdx.x;
  const int quad = lane >> 4, l16 = lane & 15;
#define TOK(t) (((long)(b * 32 + (t))) * 256 + ll)

#pragma unroll
  for (int it = 0; it < 4; ++it) {
    int chunk = it * 64 + lane;
    int t = chunk >> 3, d8 = (chunk & 7) * 8;
    bf16x8 v = *(const bf16x8*)(qkv + TOK(t) * 2304 + 1536 + hh * 64 + d8);
#pragma unroll
    for (int e = 0; e < 8; ++e) VT[(d8 + e) * 32 + t] = v[e];
  }

  bf16x8 qf[2][2];
#pragma unroll
  for (int mi = 0; mi < 2; ++mi)
#pragma unroll
    for (int kk = 0; kk < 2; ++kk)
      qf[mi][kk] = *(const bf16x8*)(qkv + TOK(mi * 16 + l16) * 2304 + hh * 64 + kk * 32 + quad * 8);

  f32x4 S[2][2];
#pragma unroll
  for (int mi = 0; mi < 2; ++mi) { S[mi][0] = fzero(); S[mi][1] = fzero(); }
#pragma unroll
  for (int nj = 0; nj < 2; ++nj)
#pragma unroll
    for (int kk = 0; kk < 2; ++kk) {
      bf16x8 kf = *(const bf16x8*)(qkv + TOK(nj * 16 + l16) * 2304 + 768 + hh * 64 + kk * 32 + quad * 8);
#pragma unroll
      for (int mi = 0; mi < 2; ++mi)
        S[mi][nj] = mfma_bf16(qf[mi][kk], kf, S[mi][nj]);
    }

#pragma unroll
  for (int mi = 0; mi < 2; ++mi)
#pragma unroll
    for (int r = 0; r < 4; ++r) {
      float m = fmaxf(S[mi][0][r], S[mi][1][r]);
      m = quad16_max(m);
      float e0 = __expf((S[mi][0][r] - m) * 0.125f);
      float e1 = __expf((S[mi][1][r] - m) * 0.125f);
      float sum = quad16_sum(e0 + e1);
      float inv = 1.f / sum;
      P[(mi * 16 + quad * 4 + r) * 32 + l16]      = f2bs(e0 * inv);
      P[(mi * 16 + quad * 4 + r) * 32 + 16 + l16] = f2bs(e1 * inv);
    }
  __syncthreads();

  f32x4 O[2][4];
#pragma unroll
  for (int mi = 0; mi < 2; ++mi)
#pragma unroll
    for (int jn = 0; jn < 4; ++jn) O[mi][jn] = fzero();
#pragma unroll
  for (int mi = 0; mi < 2; ++mi) {
    bf16x8 pf = *(const bf16x8*)&P[(mi * 16 + l16) * 32 + quad * 8];
#pragma unroll
    for (int jn = 0; jn < 4; ++jn) {
      bf16x8 vf = *(const bf16x8*)&VT[(jn * 16 + l16) * 32 + quad * 8];
      O[mi][jn] = mfma_bf16(pf, vf, O[mi][jn]);
    }
  }
#pragma unroll
  for (int mi = 0; mi < 2; ++mi)
#pragma unroll
    for (int jn = 0; jn < 4; ++jn)
#pragma unroll
      for (int r = 0; r < 4; ++r) {
        int t = mi * 16 + quad * 4 + r;
        ao[TOK(t) * 768 + hh * 64 + jn * 16 + l16] = f2bs(O[mi][jn][r]);
      }
#undef TOK
}

// ---------------------------------------------------------------------------
extern "C" void kernel_launch(void* const* d_in, const int* in_sizes, int n_in,
                              void* d_out, int out_size, void* d_ws, size_t ws_size,
                              hipStream_t stream)
{
  const float* emb     = (const float*)d_in[0];
  const float* Wq_t    = (const float*)d_in[1];
  const float* Wk_t    = (const float*)d_in[2];
  const float* Wv_t    = (const float*)d_in[3];
  const float* Wo_t    = (const float*)d_in[4];
  const float* bo_t    = (const float*)d_in[5];
  const float* Wq_s    = (const float*)d_in[6];
  const float* Wk_s    = (const float*)d_in[7];
  const float* Wv_s    = (const float*)d_in[8];
  const float* Wo_s    = (const float*)d_in[9];
  const float* bo_s    = (const float*)d_in[10];
  const float* ln_t_sc = (const float*)d_in[11];
  const float* ln_t_bi = (const float*)d_in[12];
  const float* ln_s_sc = (const float*)d_in[13];
  const float* ln_s_bi = (const float*)d_in[14];
  const float* ln2_sc  = (const float*)d_in[15];
  const float* ln2_bi  = (const float*)d_in[16];
  const float* W1      = (const float*)d_in[17];
  const float* b1      = (const float*)d_in[18];
  const float* W2      = (const float*)d_in[19];
  const float* b2      = (const float*)d_in[20];

  const long M = 16384, D = 768, QN = 2304, F = 3072;
  char* ws = (char*)d_ws;
  size_t off = 0;
  auto alloc = [&](size_t b) { char* p = ws + off; off += (b + 255) & ~(size_t)255; return p; };
  short* qkvT_t = (short*)alloc((size_t)4 * QN * D * 2);   // 14.2 MB
  short* qkvT_s = (short*)alloc((size_t)4 * QN * D * 2);   // 14.2 MB
  short* woT_t  = (short*)alloc((size_t)4 * D * D * 2);    //  4.7 MB
  short* woT_s  = (short*)alloc((size_t)4 * D * D * 2);    //  4.7 MB
  short* w1T    = (short*)alloc((size_t)4 * F * D * 2);    // 18.9 MB
  short* w2T    = (short*)alloc((size_t)4 * D * F * 2);    // 18.9 MB
  short* xb     = (short*)alloc((size_t)M * D * 2);        // 25.2 MB
  short* aob    = (short*)alloc((size_t)M * D * 2);        // 25.2 MB
  short* big    = (short*)alloc((size_t)M * F * 2);        // 100.7 MB (qkv & ffn1)
  float* h = (float*)d_out;

  hipMemcpyAsync(h, emb, (size_t)M * D * 4, hipMemcpyDeviceToDevice, stream);

  // ---- weight prep: fp32 [K][N] -> bf16 [N][K] -------------------------------
  for (int l = 0; l < 4; ++l) {
    const long wo = (long)l * D * D;
    transpose_w<<<dim3(24, 24), 256, 0, stream>>>(Wq_t + wo, qkvT_t + (long)l * QN * D,            768, 768);
    transpose_w<<<dim3(24, 24), 256, 0, stream>>>(Wk_t + wo, qkvT_t + (long)l * QN * D + D * D,    768, 768);
    transpose_w<<<dim3(24, 24), 256, 0, stream>>>(Wv_t + wo, qkvT_t + (long)l * QN * D + 2 * D * D, 768, 768);
    transpose_w<<<dim3(24, 24), 256, 0, stream>>>(Wq_s + wo, qkvT_s + (long)l * QN * D,            768, 768);
    transpose_w<<<dim3(24, 24), 256, 0, stream>>>(Wk_s + wo, qkvT_s + (long)l * QN * D + D * D,    768, 768);
    transpose_w<<<dim3(24, 24), 256, 0, stream>>>(Wv_s + wo, qkvT_s + (long)l * QN * D + 2 * D * D, 768, 768);
    transpose_w<<<dim3(24, 24), 256, 0, stream>>>(Wo_t + wo, woT_t + wo, 768, 768);
    transpose_w<<<dim3(24, 24), 256, 0, stream>>>(Wo_s + wo, woT_s + wo, 768, 768);
    transpose_w<<<dim3(96, 24), 256, 0, stream>>>(W1 + (long)l * D * F, w1T + (long)l * F * D, 768, 3072);
    transpose_w<<<dim3(24, 96), 256, 0, stream>>>(W2 + (long)l * F * D, w2T + (long)l * D * F, 3072, 768);
  }

  // ---- layers ---------------------------------------------------------------
  for (int l = 0; l < 4; ++l) {
    // time attention block
    ln_kernel<<<16384, 256, 0, stream>>>(h, ln_t_sc + l * 768, ln_t_bi + l * 768, xb);
    gemm_bt<0><<<dim3(18, 128), 256, 0, stream>>>(xb, qkvT_t + (long)l * QN * D,
        nullptr, nullptr, nullptr, big, 16384, 2304, 768);
    attn_time<<<dim3(256, 12, 2), 64, 0, stream>>>(big, aob);
    gemm_bt<1><<<dim3(6, 128), 256, 0, stream>>>(aob, woT_t + (long)l * D * D,
        bo_t + l * 768, h, h, nullptr, 16384, 768, 768);
    // space attention block
    ln_kernel<<<16384, 256, 0, stream>>>(h, ln_s_sc + l * 768, ln_s_bi + l * 768, xb);
    gemm_bt<0><<<dim3(18, 128), 256, 0, stream>>>(xb, qkvT_s + (long)l * QN * D,
        nullptr, nullptr, nullptr, big, 16384, 2304, 768);
    attn_space<<<dim3(4, 12, 64), 256, 0, stream>>>(big, aob);
    gemm_bt<1><<<dim3(6, 128), 256, 0, stream>>>(aob, woT_s + (long)l * D * D,
        bo_s + l * 768, h, h, nullptr, 16384, 768, 768);
    // FFN block
    ln_kernel<<<16384, 256, 0, stream>>>(h, ln2_sc + l * 768, ln2_bi + l * 768, xb);
    gemm_bt<2><<<dim3(24, 128), 256, 0, stream>>>(xb, w1T + (long)l * F * D,
        b1 + l * 3072, nullptr, nullptr, big, 16384, 3072, 768);
    gemm_bt<1><<<dim3(6, 128), 256, 0, stream>>>(big, w2T + (long)l * D * F,
        b2 + l * 768, h, h, nullptr, 16384, 768, 3072);
  }
}

// Round 2
// 2860.536 us; speedup vs baseline: 1.1220x; 1.1220x over previous
//
#include <hip/hip_runtime.h>

// ---------------------------------------------------------------------------
// SpatioTemporalTransformerXL forward on gfx950.
//  - residual stream h stays fp32 in d_out, updated in place
//  - LN kernels emit bf16 x; all GEMMs are bf16 MFMA (16x16x32), fp32 acc
//  - GEMM: 128x128 tile, BK=64, XOR-swizzled LDS (conflict-free ds_read_b128),
//    XCD-aware block swizzle so same-A-tile blocks share one XCD's L2
// ---------------------------------------------------------------------------

#define AS1 __attribute__((address_space(1)))
#define AS3 __attribute__((address_space(3)))

using bf16x8 = __attribute__((ext_vector_type(8))) short;   // 8 bf16 = 4 VGPRs
using f32x4  = __attribute__((ext_vector_type(4))) float;

__device__ __forceinline__ f32x4 mfma_bf16(bf16x8 a, bf16x8 b, f32x4 c) {
  return __builtin_amdgcn_mfma_f32_16x16x32_bf16(a, b, c, 0, 0, 0);
}

__device__ __forceinline__ void async16(const void* g, void* l) {
  __builtin_amdgcn_global_load_lds((const AS1 void*)g, (AS3 void*)l, 16, 0, 0);
}

// fp32 -> bf16 RNE
__device__ __forceinline__ short f2bs(float f) {
  union { float f; unsigned u; } x; x.f = f;
  unsigned r = x.u + 0x7fffu + ((x.u >> 16) & 1u);
  return (short)(r >> 16);
}

__device__ __forceinline__ f32x4 fzero() {
  f32x4 v; v[0] = 0.f; v[1] = 0.f; v[2] = 0.f; v[3] = 0.f; return v;
}

__device__ __forceinline__ float quad16_max(float v) {
  v = fmaxf(v, __shfl_xor(v, 1));
  v = fmaxf(v, __shfl_xor(v, 2));
  v = fmaxf(v, __shfl_xor(v, 4));
  v = fmaxf(v, __shfl_xor(v, 8));
  return v;
}
__device__ __forceinline__ float quad16_sum(float v) {
  v += __shfl_xor(v, 1); v += __shfl_xor(v, 2);
  v += __shfl_xor(v, 4); v += __shfl_xor(v, 8);
  return v;
}

// ---------------------------------------------------------------------------
// GEMM: C[M,N] = A[M,K](bf16) * BT[N,K]^T(bf16)  + epilogue
// MODE 0: outB = bf16(acc)                       (QKV projections)
// MODE 1: outF = acc + bias[col] + resid         (output proj / FFN2, fp32)
// MODE 2: outB = bf16(gelu_tanh(acc + bias))     (FFN1)
// 1D grid; y = (flat&7) + 8*(s/nx), x = s%nx  (s = flat>>3) so the nx blocks
// sharing an A-row-tile run consecutively on ONE XCD (flat%8 round-robin).
// LDS: row stride 64 shorts (128B); 16B granule g of row r stored at physical
// granule g ^ (r&7)  ->  ds_read_b128 hits each bank-group exactly twice
// (2-way = free, m136). global_load_lds inverts the swizzle in the global
// k-offset, keeping the LDS destination lane-contiguous.
// ---------------------------------------------------------------------------
template<int MODE>
__global__ __launch_bounds__(256) void gemm_bt(
    const short* __restrict__ A, const short* __restrict__ BT,
    const float* __restrict__ bias, const float* __restrict__ resid,
    float* __restrict__ outF, short* __restrict__ outB,
    int M, int N, int K, int nx)
{
  __shared__ __align__(16) short lA[128 * 64];
  __shared__ __align__(16) short lB[128 * 64];
  const int tid  = threadIdx.x;
  const int wave = tid >> 6, lane = tid & 63;
  const int quad = lane >> 4, l16 = lane & 15;
  const int wm = wave >> 1, wn = wave & 1;

  const unsigned flat = blockIdx.x;
  const unsigned su = flat >> 3;
  const unsigned nxu = (unsigned)nx;
  const unsigned xt = su % nxu;
  const unsigned yt = (flat & 7u) + 8u * (su / nxu);
  const long bm0 = (long)yt * 128;
  const long bn0 = (long)xt * 128;

  // staging coordinates: chunk c covers 8 rows x 64 shorts (1KB)
  const int srow = lane >> 3;                         // row within chunk
  const int skof = ((lane & 7) ^ srow) * 8;           // swizzle-inverted k-off

  f32x4 acc[4][4];
#pragma unroll
  for (int i = 0; i < 4; ++i)
#pragma unroll
    for (int j = 0; j < 4; ++j) acc[i][j] = fzero();

  for (int k0 = 0; k0 < K; k0 += 64) {
    __syncthreads();
#pragma unroll
    for (int cc = 0; cc < 4; ++cc) {
      int c = wave * 4 + cc;
      long row = c * 8 + srow;
      async16(A  + (bm0 + row) * (long)K + k0 + skof, (char*)lA + c * 1024);
      async16(BT + (bn0 + row) * (long)K + k0 + skof, (char*)lB + c * 1024);
    }
    __syncthreads();
#pragma unroll
    for (int kk = 0; kk < 2; ++kk) {
      bf16x8 a[4], b[4];
      const int pg = ((kk * 4 + quad) ^ (l16 & 7)) * 8;
#pragma unroll
      for (int i = 0; i < 4; ++i)
        a[i] = *(const bf16x8*)&lA[(wm * 64 + i * 16 + l16) * 64 + pg];
#pragma unroll
      for (int j = 0; j < 4; ++j)
        b[j] = *(const bf16x8*)&lB[(wn * 64 + j * 16 + l16) * 64 + pg];
#pragma unroll
      for (int i = 0; i < 4; ++i)
#pragma unroll
        for (int j = 0; j < 4; ++j)
          acc[i][j] = mfma_bf16(a[i], b[j], acc[i][j]);
    }
  }

#pragma unroll
  for (int i = 0; i < 4; ++i)
#pragma unroll
    for (int j = 0; j < 4; ++j)
#pragma unroll
      for (int r = 0; r < 4; ++r) {
        long gr = bm0 + wm * 64 + i * 16 + quad * 4 + r;
        long gc = bn0 + wn * 64 + j * 16 + l16;
        size_t idx = (size_t)gr * N + gc;
        float v = acc[i][j][r];
        if (MODE == 0) {
          outB[idx] = f2bs(v);
        } else if (MODE == 1) {
          outF[idx] = v + bias[gc] + resid[idx];
        } else {
          float t = v + bias[gc];
          float g = 0.5f * t * (1.f + tanhf(0.7978845608f * (t + 0.044715f * t * t * t)));
          outB[idx] = f2bs(g);
        }
      }
}

// ---------------------------------------------------------------------------
// LayerNorm: h fp32 [16384,768] -> bf16 x, one block per row, 256 threads.
// ---------------------------------------------------------------------------
__global__ __launch_bounds__(256) void ln_kernel(
    const float* __restrict__ h, const float* __restrict__ sc,
    const float* __restrict__ bi, short* __restrict__ out)
{
  const int row = blockIdx.x, tid = threadIdx.x;
  const float* hr = h + (long)row * 768;
  float x0 = hr[tid], x1 = hr[tid + 256], x2 = hr[tid + 512];
  __shared__ float red[4];
  float s = x0 + x1 + x2;
#pragma unroll
  for (int m = 32; m >= 1; m >>= 1) s += __shfl_xor(s, m);
  if ((tid & 63) == 0) red[tid >> 6] = s;
  __syncthreads();
  float mean = (red[0] + red[1] + red[2] + red[3]) * (1.f / 768.f);
  float d0 = x0 - mean, d1 = x1 - mean, d2 = x2 - mean;
  float q = d0 * d0 + d1 * d1 + d2 * d2;
#pragma unroll
  for (int m = 32; m >= 1; m >>= 1) q += __shfl_xor(q, m);
  __syncthreads();
  if ((tid & 63) == 0) red[tid >> 6] = q;
  __syncthreads();
  float var = (red[0] + red[1] + red[2] + red[3]) * (1.f / 768.f);
  float inv = rsqrtf(var + 1e-5f);
  long o = (long)row * 768;
  out[o + tid]       = f2bs(d0 * inv * sc[tid]       + bi[tid]);
  out[o + tid + 256] = f2bs(d1 * inv * sc[tid + 256] + bi[tid + 256]);
  out[o + tid + 512] = f2bs(d2 * inv * sc[tid + 512] + bi[tid + 512]);
}

// ---------------------------------------------------------------------------
// Weight transpose + bf16 cast: in fp32 [Kd][Nd] -> out bf16 [Nd][Kd]
// ---------------------------------------------------------------------------
__global__ __launch_bounds__(256) void transpose_w(
    const float* __restrict__ in, short* __restrict__ out, int Kd, int Nd)
{
  __shared__ float t[32][33];
  const int n0 = blockIdx.x * 32, k0 = blockIdx.y * 32;
  const int r = threadIdx.x >> 5, c = threadIdx.x & 31;
#pragma unroll
  for (int rr = 0; rr < 4; ++rr)
    t[r + rr * 8][c] = in[(long)(k0 + r + rr * 8) * Nd + n0 + c];
  __syncthreads();
#pragma unroll
  for (int rr = 0; rr < 4; ++rr)
    out[(long)(n0 + r + rr * 8) * Kd + k0 + c] = f2bs(t[c][r + rr * 8]);
}

// ---------------------------------------------------------------------------
// Space attention: softmax over L=256. Grid (qtile=4, head=12, b*t=64),
// 256 threads = 4 waves; each wave owns 16 q-rows. qkv row stride 2304:
// cols [0,768) Q, [768,1536) K, [1536,2304) V, packed h*64+d.
// ---------------------------------------------------------------------------
__global__ __launch_bounds__(256) void attn_space(
    const short* __restrict__ qkv, short* __restrict__ ao)
{
  __shared__ __align__(16) short VT[64 * 256];      // VT[d][l]
  __shared__ __align__(16) short P[4][16 * 256];    // per-wave P[q][l]
  const int qt = blockIdx.x, hh = blockIdx.y, bt = blockIdx.z;
  const long tok0 = (long)bt * 256;
  const int tid = threadIdx.x, wave = tid >> 6, lane = tid & 63;
  const int quad = lane >> 4, l16 = lane & 15;

  // stage V^T
#pragma unroll
  for (int it = 0; it < 8; ++it) {
    int chunk = it * 256 + tid;
    int vl = chunk >> 3, d8 = (chunk & 7) * 8;
    bf16x8 v = *(const bf16x8*)(qkv + (tok0 + vl) * 2304 + 1536 + hh * 64 + d8);
#pragma unroll
    for (int e = 0; e < 8; ++e) VT[(d8 + e) * 256 + vl] = v[e];
  }

  const int qr = qt * 64 + wave * 16;
  bf16x8 qf[2];
#pragma unroll
  for (int kk = 0; kk < 2; ++kk)
    qf[kk] = *(const bf16x8*)(qkv + (tok0 + qr + l16) * 2304 + hh * 64 + kk * 32 + quad * 8);

  f32x4 S[16];
#pragma unroll
  for (int j = 0; j < 16; ++j) S[j] = fzero();
#pragma unroll
  for (int j = 0; j < 16; ++j)
#pragma unroll
    for (int kk = 0; kk < 2; ++kk) {
      bf16x8 kf = *(const bf16x8*)(qkv + (tok0 + j * 16 + l16) * 2304 + 768 + hh * 64 + kk * 32 + quad * 8);
      S[j] = mfma_bf16(qf[kk], kf, S[j]);
    }

  // softmax rows quad*4+r  (C/D layout: col=l16, row=quad*4+reg)
#pragma unroll
  for (int r = 0; r < 4; ++r) {
    float m = -1e30f;
#pragma unroll
    for (int j = 0; j < 16; ++j) m = fmaxf(m, S[j][r]);
    m = quad16_max(m);
    float sum = 0.f;
#pragma unroll
    for (int j = 0; j < 16; ++j) {
      float e = __expf((S[j][r] - m) * 0.125f);
      S[j][r] = e; sum += e;
    }
    sum = quad16_sum(sum);
    float inv = 1.f / sum;
#pragma unroll
    for (int j = 0; j < 16; ++j)
      P[wave][(quad * 4 + r) * 256 + j * 16 + l16] = f2bs(S[j][r] * inv);
  }
  __syncthreads();

  // O = P (A-layout from LDS) * V (B-layout from VT)
  f32x4 O[4];
#pragma unroll
  for (int jn = 0; jn < 4; ++jn) O[jn] = fzero();
  for (int kk = 0; kk < 8; ++kk) {
    bf16x8 pf = *(const bf16x8*)&P[wave][l16 * 256 + kk * 32 + quad * 8];
#pragma unroll
    for (int jn = 0; jn < 4; ++jn) {
      bf16x8 vf = *(const bf16x8*)&VT[(jn * 16 + l16) * 256 + kk * 32 + quad * 8];
      O[jn] = mfma_bf16(pf, vf, O[jn]);
    }
  }
#pragma unroll
  for (int jn = 0; jn < 4; ++jn)
#pragma unroll
    for (int r = 0; r < 4; ++r) {
      int row = qr + quad * 4 + r;
      ao[(tok0 + row) * 768 + hh * 64 + jn * 16 + l16] = f2bs(O[jn][r]);
    }
}

// ---------------------------------------------------------------------------
// Time attention: softmax over T=32. Grid (l=256, head=12, b=2), 1 wave.
// token(t) = (b*32+t)*256 + l
// ---------------------------------------------------------------------------
__global__ __launch_bounds__(64) void attn_time(
    const short* __restrict__ qkv, short* __restrict__ ao)
{
  __shared__ __align__(16) short VT[64 * 32];   // VT[d][t]
  __shared__ __align__(16) short P[32 * 32];    // P[t_q][t_k]
  const int ll = blockIdx.x, hh = blockIdx.y, b = blockIdx.z;
  const int lane = threadIdx.x;
  const int quad = lane >> 4, l16 = lane & 15;
#define TOK(t) (((long)(b * 32 + (t))) * 256 + ll)

#pragma unroll
  for (int it = 0; it < 4; ++it) {
    int chunk = it * 64 + lane;
    int t = chunk >> 3, d8 = (chunk & 7) * 8;
    bf16x8 v = *(const bf16x8*)(qkv + TOK(t) * 2304 + 1536 + hh * 64 + d8);
#pragma unroll
    for (int e = 0; e < 8; ++e) VT[(d8 + e) * 32 + t] = v[e];
  }

  bf16x8 qf[2][2];
#pragma unroll
  for (int mi = 0; mi < 2; ++mi)
#pragma unroll
    for (int kk = 0; kk < 2; ++kk)
      qf[mi][kk] = *(const bf16x8*)(qkv + TOK(mi * 16 + l16) * 2304 + hh * 64 + kk * 32 + quad * 8);

  f32x4 S[2][2];
#pragma unroll
  for (int mi = 0; mi < 2; ++mi) { S[mi][0] = fzero(); S[mi][1] = fzero(); }
#pragma unroll
  for (int nj = 0; nj < 2; ++nj)
#pragma unroll
    for (int kk = 0; kk < 2; ++kk) {
      bf16x8 kf = *(const bf16x8*)(qkv + TOK(nj * 16 + l16) * 2304 + 768 + hh * 64 + kk * 32 + quad * 8);
#pragma unroll
      for (int mi = 0; mi < 2; ++mi)
        S[mi][nj] = mfma_bf16(qf[mi][kk], kf, S[mi][nj]);
    }

#pragma unroll
  for (int mi = 0; mi < 2; ++mi)
#pragma unroll
    for (int r = 0; r < 4; ++r) {
      float m = fmaxf(S[mi][0][r], S[mi][1][r]);
      m = quad16_max(m);
      float e0 = __expf((S[mi][0][r] - m) * 0.125f);
      float e1 = __expf((S[mi][1][r] - m) * 0.125f);
      float sum = quad16_sum(e0 + e1);
      float inv = 1.f / sum;
      P[(mi * 16 + quad * 4 + r) * 32 + l16]      = f2bs(e0 * inv);
      P[(mi * 16 + quad * 4 + r) * 32 + 16 + l16] = f2bs(e1 * inv);
    }
  __syncthreads();

  f32x4 O[2][4];
#pragma unroll
  for (int mi = 0; mi < 2; ++mi)
#pragma unroll
    for (int jn = 0; jn < 4; ++jn) O[mi][jn] = fzero();
#pragma unroll
  for (int mi = 0; mi < 2; ++mi) {
    bf16x8 pf = *(const bf16x8*)&P[(mi * 16 + l16) * 32 + quad * 8];
#pragma unroll
    for (int jn = 0; jn < 4; ++jn) {
      bf16x8 vf = *(const bf16x8*)&VT[(jn * 16 + l16) * 32 + quad * 8];
      O[mi][jn] = mfma_bf16(pf, vf, O[mi][jn]);
    }
  }
#pragma unroll
  for (int mi = 0; mi < 2; ++mi)
#pragma unroll
    for (int jn = 0; jn < 4; ++jn)
#pragma unroll
      for (int r = 0; r < 4; ++r) {
        int t = mi * 16 + quad * 4 + r;
        ao[TOK(t) * 768 + hh * 64 + jn * 16 + l16] = f2bs(O[mi][jn][r]);
      }
#undef TOK
}

// ---------------------------------------------------------------------------
extern "C" void kernel_launch(void* const* d_in, const int* in_sizes, int n_in,
                              void* d_out, int out_size, void* d_ws, size_t ws_size,
                              hipStream_t stream)
{
  const float* emb     = (const float*)d_in[0];
  const float* Wq_t    = (const float*)d_in[1];
  const float* Wk_t    = (const float*)d_in[2];
  const float* Wv_t    = (const float*)d_in[3];
  const float* Wo_t    = (const float*)d_in[4];
  const float* bo_t    = (const float*)d_in[5];
  const float* Wq_s    = (const float*)d_in[6];
  const float* Wk_s    = (const float*)d_in[7];
  const float* Wv_s    = (const float*)d_in[8];
  const float* Wo_s    = (const float*)d_in[9];
  const float* bo_s    = (const float*)d_in[10];
  const float* ln_t_sc = (const float*)d_in[11];
  const float* ln_t_bi = (const float*)d_in[12];
  const float* ln_s_sc = (const float*)d_in[13];
  const float* ln_s_bi = (const float*)d_in[14];
  const float* ln2_sc  = (const float*)d_in[15];
  const float* ln2_bi  = (const float*)d_in[16];
  const float* W1      = (const float*)d_in[17];
  const float* b1      = (const float*)d_in[18];
  const float* W2      = (const float*)d_in[19];
  const float* b2      = (const float*)d_in[20];

  const long M = 16384, D = 768, QN = 2304, F = 3072;
  char* ws = (char*)d_ws;
  size_t off = 0;
  auto alloc = [&](size_t b) { char* p = ws + off; off += (b + 255) & ~(size_t)255; return p; };
  short* qkvT_t = (short*)alloc((size_t)4 * QN * D * 2);   // 14.2 MB
  short* qkvT_s = (short*)alloc((size_t)4 * QN * D * 2);   // 14.2 MB
  short* woT_t  = (short*)alloc((size_t)4 * D * D * 2);    //  4.7 MB
  short* woT_s  = (short*)alloc((size_t)4 * D * D * 2);    //  4.7 MB
  short* w1T    = (short*)alloc((size_t)4 * F * D * 2);    // 18.9 MB
  short* w2T    = (short*)alloc((size_t)4 * D * F * 2);    // 18.9 MB
  short* xb     = (short*)alloc((size_t)M * D * 2);        // 25.2 MB
  short* aob    = (short*)alloc((size_t)M * D * 2);        // 25.2 MB
  short* big    = (short*)alloc((size_t)M * F * 2);        // 100.7 MB (qkv & ffn1)
  float* h = (float*)d_out;

  hipMemcpyAsync(h, emb, (size_t)M * D * 4, hipMemcpyDeviceToDevice, stream);

  // ---- weight prep: fp32 [K][N] -> bf16 [N][K] -------------------------------
  for (int l = 0; l < 4; ++l) {
    const long wo = (long)l * D * D;
    transpose_w<<<dim3(24, 24), 256, 0, stream>>>(Wq_t + wo, qkvT_t + (long)l * QN * D,            768, 768);
    transpose_w<<<dim3(24, 24), 256, 0, stream>>>(Wk_t + wo, qkvT_t + (long)l * QN * D + D * D,    768, 768);
    transpose_w<<<dim3(24, 24), 256, 0, stream>>>(Wv_t + wo, qkvT_t + (long)l * QN * D + 2 * D * D, 768, 768);
    transpose_w<<<dim3(24, 24), 256, 0, stream>>>(Wq_s + wo, qkvT_s + (long)l * QN * D,            768, 768);
    transpose_w<<<dim3(24, 24), 256, 0, stream>>>(Wk_s + wo, qkvT_s + (long)l * QN * D + D * D,    768, 768);
    transpose_w<<<dim3(24, 24), 256, 0, stream>>>(Wv_s + wo, qkvT_s + (long)l * QN * D + 2 * D * D, 768, 768);
    transpose_w<<<dim3(24, 24), 256, 0, stream>>>(Wo_t + wo, woT_t + wo, 768, 768);
    transpose_w<<<dim3(24, 24), 256, 0, stream>>>(Wo_s + wo, woT_s + wo, 768, 768);
    transpose_w<<<dim3(96, 24), 256, 0, stream>>>(W1 + (long)l * D * F, w1T + (long)l * F * D, 768, 3072);
    transpose_w<<<dim3(24, 96), 256, 0, stream>>>(W2 + (long)l * F * D, w2T + (long)l * D * F, 3072, 768);
  }

  // ---- layers ---------------------------------------------------------------
  for (int l = 0; l < 4; ++l) {
    // time attention block
    ln_kernel<<<16384, 256, 0, stream>>>(h, ln_t_sc + l * 768, ln_t_bi + l * 768, xb);
    gemm_bt<0><<<18 * 128, 256, 0, stream>>>(xb, qkvT_t + (long)l * QN * D,
        nullptr, nullptr, nullptr, big, 16384, 2304, 768, 18);
    attn_time<<<dim3(256, 12, 2), 64, 0, stream>>>(big, aob);
    gemm_bt<1><<<6 * 128, 256, 0, stream>>>(aob, woT_t + (long)l * D * D,
        bo_t + l * 768, h, h, nullptr, 16384, 768, 768, 6);
    // space attention block
    ln_kernel<<<16384, 256, 0, stream>>>(h, ln_s_sc + l * 768, ln_s_bi + l * 768, xb);
    gemm_bt<0><<<18 * 128, 256, 0, stream>>>(xb, qkvT_s + (long)l * QN * D,
        nullptr, nullptr, nullptr, big, 16384, 2304, 768, 18);
    attn_space<<<dim3(4, 12, 64), 256, 0, stream>>>(big, aob);
    gemm_bt<1><<<6 * 128, 256, 0, stream>>>(aob, woT_s + (long)l * D * D,
        bo_s + l * 768, h, h, nullptr, 16384, 768, 768, 6);
    // FFN block
    ln_kernel<<<16384, 256, 0, stream>>>(h, ln2_sc + l * 768, ln2_bi + l * 768, xb);
    gemm_bt<2><<<24 * 128, 256, 0, stream>>>(xb, w1T + (long)l * F * D,
        b1 + l * 3072, nullptr, nullptr, big, 16384, 3072, 768, 24);
    gemm_bt<1><<<6 * 128, 256, 0, stream>>>(big, w2T + (long)l * D * F,
        b2 + l * 768, h, h, nullptr, 16384, 768, 3072, 6);
  }
}